// Round 7
// baseline (119.084 us; speedup 1.0000x reference)
//
#include <hip/hip_runtime.h>

#define GRIDN 31
#define ROW   961              // floats per heatmap
#define BJ    65536            // rows
#define NQUADS (BJ / 4)        // 16384 quads of 4 rows = 3844 floats = 961 float4
#define WPB 4
#define QPW 2                  // quads per wave
#define NBLOCKS (NQUADS / (WPB * QPW))   // 2048

typedef float v4f __attribute__((ext_vector_type(4)));

__global__ __launch_bounds__(256) void soft_argmax_loss_kernel(
    const float* __restrict__ pred,
    const float* __restrict__ gt,
    float* __restrict__ out)
{
    const int lane = threadIdx.x & 63;
    const int wave = threadIdx.x >> 6;
    const int gw   = blockIdx.x * WPB + wave;

    // ---- packed per-lane weights: slot j = lane+64k covers e = 4j+c, c=0..3
    // of the 3844-float quad. ep = e mod 961 -> (x,y); invalid (j>960) -> 0.
    unsigned xw[16], yw[16];
    #pragma unroll
    for (int k = 0; k < 16; ++k) {
        unsigned xp = 0, yp = 0;
        const int j = lane + 64 * k;
        #pragma unroll
        for (int c = 0; c < 4; ++c) {
            int e  = 4 * j + c;
            int ep = e % ROW;
            int y  = ep / GRIDN;
            int x  = ep - GRIDN * y;
            if (j > 960) { x = 0; y = 0; }
            xp |= (unsigned)x << (8 * c);
            yp |= (unsigned)y << (8 * c);
        }
        xw[k] = xp; yw[k] = yp;
    }

    const v4f* __restrict__ p4 = (const v4f*)pred;
    const v4f* __restrict__ g4 = (const v4f*)gt;

    float wsum = 0.0f;

    #pragma unroll 1
    for (int q = 0; q < QPW; ++q) {
        const int Q = gw * QPW + q;
        const size_t base4 = (size_t)Q * ROW;        // float4 units

        // row accumulators + mixed-slot groups (k=3,7,11 straddle rows;
        // split by compile-time c, routed by lane threshold at epilogue)
        float r0x=0,r0y=0, r1x=0,r1y=0, r2x=0,r2y=0, r3x=0,r3y=0;
        float a3x=0,a3y=0, b3x=0,b3y=0;     // k=3: c0 | c123  (lane thr 48)
        float a7x=0,a7y=0, b7x=0,b7y=0;     // k=7: c01 | c23  (lane thr 32)
        float a11x=0,a11y=0, b11x=0,b11y=0; // k=11: c012 | c3 (lane thr 16)

        #pragma unroll
        for (int k = 0; k < 16; ++k) {
            const int j  = lane + 64 * k;
            const int jc = (k == 15) ? 960 : j;      // clamp tail (weights 0)
            // pred: non-temporal (no cache allocation -> target stays L3-resident)
            v4f pv = __builtin_nontemporal_load(&p4[base4 + jc]);
            v4f gv = g4[base4 + jc];
            float d[4] = { pv.x - gv.x, pv.y - gv.y, pv.z - gv.z, pv.w - gv.w };
            #pragma unroll
            for (int c = 0; c < 4; ++c) {
                float wx = (float)((xw[k] >> (8 * c)) & 0xffu);  // v_cvt_f32_ubyte
                float wy = (float)((yw[k] >> (8 * c)) & 0xffu);
                if (k <= 2)       { r0x = fmaf(d[c], wx, r0x); r0y = fmaf(d[c], wy, r0y); }
                else if (k == 3)  {
                    if (c == 0)   { a3x = fmaf(d[c], wx, a3x); a3y = fmaf(d[c], wy, a3y); }
                    else          { b3x = fmaf(d[c], wx, b3x); b3y = fmaf(d[c], wy, b3y); }
                }
                else if (k <= 6)  { r1x = fmaf(d[c], wx, r1x); r1y = fmaf(d[c], wy, r1y); }
                else if (k == 7)  {
                    if (c <= 1)   { a7x = fmaf(d[c], wx, a7x); a7y = fmaf(d[c], wy, a7y); }
                    else          { b7x = fmaf(d[c], wx, b7x); b7y = fmaf(d[c], wy, b7y); }
                }
                else if (k <= 10) { r2x = fmaf(d[c], wx, r2x); r2y = fmaf(d[c], wy, r2y); }
                else if (k == 11) {
                    if (c <= 2)   { a11x = fmaf(d[c], wx, a11x); a11y = fmaf(d[c], wy, a11y); }
                    else          { b11x = fmaf(d[c], wx, b11x); b11y = fmaf(d[c], wy, b11y); }
                }
                else              { r3x = fmaf(d[c], wx, r3x); r3y = fmaf(d[c], wy, r3y); }
            }
        }

        // route mixed groups (boundary lanes' straddle elements have weight 0)
        r0x += (lane <= 48 ? a3x : 0.f) + (lane < 48 ? b3x : 0.f);
        r0y += (lane <= 48 ? a3y : 0.f) + (lane < 48 ? b3y : 0.f);
        r1x += (lane >  48 ? a3x : 0.f) + (lane >= 48 ? b3x : 0.f)
             + (lane <= 32 ? a7x : 0.f) + (lane < 32 ? b7x : 0.f);
        r1y += (lane >  48 ? a3y : 0.f) + (lane >= 48 ? b3y : 0.f)
             + (lane <= 32 ? a7y : 0.f) + (lane < 32 ? b7y : 0.f);
        r2x += (lane >  32 ? a7x : 0.f) + (lane >= 32 ? b7x : 0.f)
             + (lane <= 16 ? a11x : 0.f) + (lane < 16 ? b11x : 0.f);
        r2y += (lane >  32 ? a7y : 0.f) + (lane >= 32 ? b7y : 0.f)
             + (lane <= 16 ? a11y : 0.f) + (lane < 16 ? b11y : 0.f);
        r3x += (lane >  16 ? a11x : 0.f) + (lane >= 16 ? b11x : 0.f);
        r3y += (lane >  16 ? a11y : 0.f) + (lane >= 16 ? b11y : 0.f);

        // butterfly reduce 8 values
        #pragma unroll
        for (int off = 32; off; off >>= 1) {
            r0x += __shfl_xor(r0x, off); r0y += __shfl_xor(r0y, off);
            r1x += __shfl_xor(r1x, off); r1y += __shfl_xor(r1y, off);
            r2x += __shfl_xor(r2x, off); r2y += __shfl_xor(r2y, off);
            r3x += __shfl_xor(r3x, off); r3y += __shfl_xor(r3y, off);
        }

        const float s31 = 1.0f / 31.0f;
        float x0 = r0x * s31, y0 = r0y * s31;
        float x1 = r1x * s31, y1 = r1y * s31;
        float x2 = r2x * s31, y2 = r2y * s31;
        float x3 = r3x * s31, y3 = r3y * s31;
        wsum += 0.5f * (sqrtf(x0*x0 + y0*y0) + sqrtf(x1*x1 + y1*y1)
                      + sqrtf(x2*x2 + y2*y2) + sqrtf(x3*x3 + y3*y3));
    }

    __shared__ float s[WPB];
    if (lane == 0) s[wave] = wsum;
    __syncthreads();
    if (threadIdx.x == 0) {
        atomicAdd(out, (s[0] + s[1] + s[2] + s[3]) * (1.0f / (float)BJ));
    }
}

extern "C" void kernel_launch(void* const* d_in, const int* in_sizes, int n_in,
                              void* d_out, int out_size, void* d_ws, size_t ws_size,
                              hipStream_t stream) {
    const float* pred = (const float*)d_in[0];
    const float* gt   = (const float*)d_in[1];
    float* out = (float*)d_out;

    // d_out poisoned once, never re-poisoned between replays: zero every launch.
    (void)hipMemsetAsync(out, 0, sizeof(float), stream);

    soft_argmax_loss_kernel<<<NBLOCKS, 256, 0, stream>>>(pred, gt, out);
}

// Round 8
// 82.675 us; speedup vs baseline: 1.4404x; 1.4404x over previous
//
#include <hip/hip_runtime.h>

#define GRIDN 31
#define ROW   961            // 31*31
#define BJ    65536          // 1024 * 64 rows
#define NPAIRS (BJ / 2)      // 32768 row-pairs, each 1922 floats = 961 float2
#define NBLOCKS 2048
#define WPB 4                // waves per block
#define PAIRS_PER_WAVE (NPAIRS / (NBLOCKS * WPB))   // 4

typedef float v2f __attribute__((ext_vector_type(2)));   // builtin-compatible

__global__ __launch_bounds__(256) void soft_argmax_loss_kernel(
    const float* __restrict__ pred,
    const float* __restrict__ gt,
    float* __restrict__ out)
{
    const int lane = threadIdx.x & 63;
    const int wave = threadIdx.x >> 6;
    const int gw   = blockIdx.x * WPB + wave;       // 0..8191

    // ---- hoisted weights: fixed per (lane, k, c) across ALL pairs ----
    // slot j = lane + 64k covers elements e = 2j, 2j+1 of the 1922-elem pair.
    // e < 961 -> row A, e >= 961 -> row B with e' = e - 961.
    // (e == 961 has (x,y) = (0,0): zero contribution, routing irrelevant.)
    float wx[16][2], wy[16][2];
    #pragma unroll
    for (int k = 0; k < 16; ++k) {
        const int j = lane + 64 * k;
        #pragma unroll
        for (int c = 0; c < 2; ++c) {
            int e  = 2 * j + c;
            int ep = (e >= ROW) ? (e - ROW) : e;
            int y  = ep / GRIDN;
            int x  = ep - GRIDN * y;
            bool valid = (j <= 960);                 // k=15: only lane 0 real
            wx[k][c] = valid ? (float)x : 0.0f;
            wy[k][c] = valid ? (float)y : 0.0f;
        }
    }

    const v2f* __restrict__ p2 = (const v2f*)pred;
    const v2f* __restrict__ g2 = (const v2f*)gt;

    float wsum = 0.0f;

    #pragma unroll 1
    for (int pr = 0; pr < PAIRS_PER_WAVE; ++pr) {
        const int P = gw * PAIRS_PER_WAVE + pr;
        const size_t base = (size_t)P * ROW;         // in float2 units

        float dxA = 0.f, dyA = 0.f;                  // row 2P
        float dxM = 0.f, dyM = 0.f;                  // k==7 mixed slot
        float dxB = 0.f, dyB = 0.f;                  // row 2P+1

        #pragma unroll
        for (int k = 0; k < 16; ++k) {
            const int j  = lane + 64 * k;
            const int jc = (k == 15) ? 960 : j;      // clamp tail (weights 0 off-lane0)
            // pred: NON-TEMPORAL — stream, don't allocate in cache, so it
            // cannot victimize the L3-resident target input.
            v2f pv = __builtin_nontemporal_load(&p2[base + jc]);
            // target: normal cached load — 252 MB fits the 256 MB L3.
            v2f gv = g2[base + jc];
            float d0 = pv.x - gv.x;
            float d1 = pv.y - gv.y;
            if (k <= 6) {
                dxA = fmaf(d0, wx[k][0], dxA); dyA = fmaf(d0, wy[k][0], dyA);
                dxA = fmaf(d1, wx[k][1], dxA); dyA = fmaf(d1, wy[k][1], dyA);
            } else if (k == 7) {
                dxM = fmaf(d0, wx[k][0], dxM); dyM = fmaf(d0, wy[k][0], dyM);
                dxM = fmaf(d1, wx[k][1], dxM); dyM = fmaf(d1, wy[k][1], dyM);
            } else {
                dxB = fmaf(d0, wx[k][0], dxB); dyB = fmaf(d0, wy[k][0], dyB);
                dxB = fmaf(d1, wx[k][1], dxB); dyB = fmaf(d1, wy[k][1], dyB);
            }
        }

        // route the mixed k==7 slot: lanes 0..32 -> row A, 33..63 -> row B
        const bool toA = (lane <= 32);
        dxA += toA ? dxM : 0.f;  dyA += toA ? dyM : 0.f;
        dxB += toA ? 0.f : dxM;  dyB += toA ? 0.f : dyM;

        // wave butterfly reduce (4 values)
        #pragma unroll
        for (int off = 32; off; off >>= 1) {
            dxA += __shfl_xor(dxA, off); dyA += __shfl_xor(dyA, off);
            dxB += __shfl_xor(dxB, off); dyB += __shfl_xor(dyB, off);
        }

        const float s31 = 1.0f / 31.0f;
        float ax = dxA * s31, ay = dyA * s31;
        float bx = dxB * s31, by = dyB * s31;
        wsum += 0.5f * (sqrtf(ax * ax + ay * ay) + sqrtf(bx * bx + by * by));
    }

    __shared__ float s[WPB];
    if (lane == 0) s[wave] = wsum;
    __syncthreads();
    if (threadIdx.x == 0) {
        atomicAdd(out, (s[0] + s[1] + s[2] + s[3]) * (1.0f / (float)BJ));
    }
}

extern "C" void kernel_launch(void* const* d_in, const int* in_sizes, int n_in,
                              void* d_out, int out_size, void* d_ws, size_t ws_size,
                              hipStream_t stream) {
    const float* pred = (const float*)d_in[0];
    const float* gt   = (const float*)d_in[1];
    float* out = (float*)d_out;

    // d_out is poisoned once and never re-poisoned between replays: zero it
    // every launch (async memset is graph-capture safe).
    (void)hipMemsetAsync(out, 0, sizeof(float), stream);

    soft_argmax_loss_kernel<<<NBLOCKS, 256, 0, stream>>>(pred, gt, out);
}